// Round 6
// baseline (1170.537 us; speedup 1.0000x reference)
//
#include <hip/hip_runtime.h>

#define N_ROWS 8192
#define K_CODES 8192
#define D_DIM 512

typedef unsigned long long u64;

// ---------------------------------------------------------------------------
// numpy pairwise summation of squares (bit-exact, unchanged from passing R3-R5).
// ---------------------------------------------------------------------------
__device__ __forceinline__ float pw_base128_sq(const float* __restrict__ p) {
  float r0 = __fmul_rn(p[0], p[0]);
  float r1 = __fmul_rn(p[1], p[1]);
  float r2 = __fmul_rn(p[2], p[2]);
  float r3 = __fmul_rn(p[3], p[3]);
  float r4 = __fmul_rn(p[4], p[4]);
  float r5 = __fmul_rn(p[5], p[5]);
  float r6 = __fmul_rn(p[6], p[6]);
  float r7 = __fmul_rn(p[7], p[7]);
  for (int i = 8; i < 128; i += 8) {
    r0 = __fadd_rn(r0, __fmul_rn(p[i + 0], p[i + 0]));
    r1 = __fadd_rn(r1, __fmul_rn(p[i + 1], p[i + 1]));
    r2 = __fadd_rn(r2, __fmul_rn(p[i + 2], p[i + 2]));
    r3 = __fadd_rn(r3, __fmul_rn(p[i + 3], p[i + 3]));
    r4 = __fadd_rn(r4, __fmul_rn(p[i + 4], p[i + 4]));
    r5 = __fadd_rn(r5, __fmul_rn(p[i + 5], p[i + 5]));
    r6 = __fadd_rn(r6, __fmul_rn(p[i + 6], p[i + 6]));
    r7 = __fadd_rn(r7, __fmul_rn(p[i + 7], p[i + 7]));
  }
  return __fadd_rn(__fadd_rn(__fadd_rn(r0, r1), __fadd_rn(r2, r3)),
                   __fadd_rn(__fadd_rn(r4, r5), __fadd_rn(r6, r7)));
}

__device__ __forceinline__ float pw_sq_512(const float* __restrict__ p) {
  float b0 = pw_base128_sq(p);
  float b1 = pw_base128_sq(p + 128);
  float b2 = pw_base128_sq(p + 256);
  float b3 = pw_base128_sq(p + 384);
  return __fadd_rn(__fadd_rn(b0, b1), __fadd_rn(b2, b3));
}

__global__ __launch_bounds__(256) void vq_sq(const float* __restrict__ x,
                                             const float* __restrict__ emb,
                                             float* __restrict__ x_sq,
                                             float* __restrict__ e_sq) {
  const int tid = blockIdx.x * 256 + threadIdx.x;
  if (tid < N_ROWS) {
    x_sq[tid] = pw_sq_512(x + tid * D_DIM);
  } else {
    const int k = tid - N_ROWS;
    e_sq[k] = pw_sq_512(emb + k * D_DIM);
  }
}

// ---------------------------------------------------------------------------
// Kernel 2: distance + argmin. Tile 64n x 256k per block (8 waves, 512 thr).
// Double-buffered LDS (2 x 32 KB), stage(next) issued before compute(cur),
// one vmcnt(0)+barrier per 32-dd chunk. launch_bounds(512,2): VGPR cap 256
// so the 64 f32 accumulators live in arch VGPRs (R5's (512,4) forced 64 VGPR
// -> AGPR/scratch shuffling = half the VALU issue wasted).
// LDS: 256 k-rows x 32 dd; quad-XOR swizzle with FULL row-hash
// f(row) = ((row>>3)&7) ^ ((row>>6)&3)  (R5 missed the >>6 term -> 4-way
// conflicts among lanes 16 apart).
// FMA chain per output bit-identical to R3/R4/R5 (ascending dd, split@384).
// ---------------------------------------------------------------------------
__device__ __forceinline__ void compute_chunk(const float* __restrict__ esb,
                                              const float* __restrict__ xw,
                                              int dd0, int lane,
                                              float (&acc)[8][4]) {
  const int ebase = lane * 128;
  const int lm = ((lane >> 1) & 7) ^ ((lane >> 4) & 3);  // f(4*lane+j), j<4
#pragma unroll
  for (int g = 0; g < 8; ++g) {
    const float* p = esb + ebase + 4 * (g ^ lm);
    const float4 ev0 = *reinterpret_cast<const float4*>(p);
    const float4 ev1 = *reinterpret_cast<const float4*>(p + 32);
    const float4 ev2 = *reinterpret_cast<const float4*>(p + 64);
    const float4 ev3 = *reinterpret_cast<const float4*>(p + 96);
#pragma unroll
    for (int r = 0; r < 8; ++r) {
      const float4 xv =
          *reinterpret_cast<const float4*>(xw + r * D_DIM + dd0 + 4 * g);
      float a0 = acc[r][0], a1 = acc[r][1], a2 = acc[r][2], a3 = acc[r][3];
      a0 = __fmaf_rn(xv.x, ev0.x, a0);
      a0 = __fmaf_rn(xv.y, ev0.y, a0);
      a0 = __fmaf_rn(xv.z, ev0.z, a0);
      a0 = __fmaf_rn(xv.w, ev0.w, a0);
      a1 = __fmaf_rn(xv.x, ev1.x, a1);
      a1 = __fmaf_rn(xv.y, ev1.y, a1);
      a1 = __fmaf_rn(xv.z, ev1.z, a1);
      a1 = __fmaf_rn(xv.w, ev1.w, a1);
      a2 = __fmaf_rn(xv.x, ev2.x, a2);
      a2 = __fmaf_rn(xv.y, ev2.y, a2);
      a2 = __fmaf_rn(xv.z, ev2.z, a2);
      a2 = __fmaf_rn(xv.w, ev2.w, a2);
      a3 = __fmaf_rn(xv.x, ev3.x, a3);
      a3 = __fmaf_rn(xv.y, ev3.y, a3);
      a3 = __fmaf_rn(xv.z, ev3.z, a3);
      a3 = __fmaf_rn(xv.w, ev3.w, a3);
      acc[r][0] = a0; acc[r][1] = a1; acc[r][2] = a2; acc[r][3] = a3;
    }
  }
}

// One global_load_lds: lane t stages 16 B to linear LDS (4t+2048I floats);
// global source dd-quad pre-swizzled by f(row) with row = (t>>3)+64I:
// f = ((t>>6)&7) ^ (I&3).
#define STAGE1(BUF, DD0, I)                                                    \
  __builtin_amdgcn_global_load_lds(                                            \
      (const __attribute__((address_space(1))) void*)(                         \
          e + (size_t)(k0 + (t >> 3) + 64 * (I)) * D_DIM + (DD0) +             \
          4 * ((t & 7) ^ ((t >> 6) & 7) ^ ((I) & 3))),                         \
      (__attribute__((address_space(3))) void*)(&es[BUF][4 * t + 2048 * (I)]), \
      16, 0, 0)
#define STAGE(BUF, DD0)                                                        \
  do {                                                                         \
    STAGE1(BUF, DD0, 0);                                                       \
    STAGE1(BUF, DD0, 1);                                                       \
    STAGE1(BUF, DD0, 2);                                                       \
    STAGE1(BUF, DD0, 3);                                                       \
  } while (0)

__global__ __launch_bounds__(512, 2) void vq_dist(
    const float* __restrict__ x, const float* __restrict__ e,
    const float* __restrict__ x_sq, const float* __restrict__ e_sq,
    u64* __restrict__ slots) {
  __shared__ float es[2][8192];  // 2 x 32 KB

  const int t = threadIdx.x;
  const int lane = t & 63;

  // XCD-aware bijective swizzle: 4096 blocks -> 512/XCD; one XCD works
  // through 128 consecutive n-blocks of the same k-panel (512 KB, L2-hot).
  const int bx = blockIdx.x;
  const int swz = (bx & 7) * 512 + (bx >> 3);
  const int kb = swz >> 7;    // 0..31
  const int nb = swz & 127;   // 0..127
  const int k0 = kb * 256;
  const int n0w = __builtin_amdgcn_readfirstlane(nb * 64 + (t >> 6) * 8);
  const float* xw = x + (size_t)n0w * D_DIM;

  float accA[8][4], accB[8][4];
#pragma unroll
  for (int r = 0; r < 8; ++r)
#pragma unroll
    for (int j = 0; j < 4; ++j) { accA[r][j] = 0.0f; accB[r][j] = 0.0f; }

  // Prologue: fill buffer 0 with chunk 0.
  STAGE(0, 0);
  asm volatile("s_waitcnt vmcnt(0)" ::: "memory");
  __syncthreads();

  // Phase A: chunks 0..11 (dd < 384).
#pragma unroll 1
  for (int c = 0; c < 12; ++c) {
    STAGE((c + 1) & 1, (c + 1) * 32);
    compute_chunk(&es[c & 1][0], xw, c * 32, lane, accA);
    asm volatile("s_waitcnt vmcnt(0)" ::: "memory");
    __syncthreads();
  }
  // Phase B: chunks 12..15 (dd >= 384).
#pragma unroll 1
  for (int c = 12; c < 16; ++c) {
    if (c < 15) STAGE((c + 1) & 1, (c + 1) * 32);
    compute_chunk(&es[c & 1][0], xw, c * 32, lane, accB);
    asm volatile("s_waitcnt vmcnt(0)" ::: "memory");
    __syncthreads();
  }

  // Epilogue: dist = fl(fl(x_sq - 2*dot) + e_sq); packed-key argmin.
  const float4 xsqa = *reinterpret_cast<const float4*>(x_sq + n0w);
  const float4 xsqb = *reinterpret_cast<const float4*>(x_sq + n0w + 4);
  const float xsq[8] = {xsqa.x, xsqa.y, xsqa.z, xsqa.w,
                        xsqb.x, xsqb.y, xsqb.z, xsqb.w};
  const int klane = k0 + lane * 4;
  const float4 esq = *reinterpret_cast<const float4*>(e_sq + klane);
  const float esqv[4] = {esq.x, esq.y, esq.z, esq.w};

#pragma unroll
  for (int r = 0; r < 8; ++r) {
    u64 best = ~0ULL;
#pragma unroll
    for (int j = 0; j < 4; ++j) {
      float dot = __fadd_rn(accA[r][j], accB[r][j]);
      float dist = __fadd_rn(__fsub_rn(xsq[r], __fmul_rn(2.0f, dot)), esqv[j]);
      unsigned int b = __float_as_uint(dist);
      unsigned int sb = (b & 0x80000000u) ? ~b : (b | 0x80000000u);
      u64 key = ((u64)sb << 32) | (unsigned)(klane + j);
      best = best < key ? best : key;
    }
#pragma unroll
    for (int off = 32; off > 0; off >>= 1) {
      u64 o = __shfl_xor((unsigned long long)best, off, 64);
      best = best < o ? best : o;
    }
    if (lane == 0) atomicMin(&slots[n0w + r], best);
  }
}

// ---------------------------------------------------------------------------
// Kernel 3: gather quantized rows (one wave per row), f32 outputs, loss
// partials into 256 hashed f64 buckets.
// ---------------------------------------------------------------------------
__global__ __launch_bounds__(256) void vq_out(
    const float* __restrict__ x, const float* __restrict__ e,
    const u64* __restrict__ slots, float* __restrict__ out_q,
    float* __restrict__ out_idx, double* __restrict__ loss_part) {
  const int t = threadIdx.x;
  const int w = t >> 6, lane = t & 63;
  const int n = blockIdx.x * 4 + w;
  const int idx = (int)(slots[n] & 0xFFFFFFFFULL);
  const float4* qr = (const float4*)(e + (size_t)idx * D_DIM);
  const float4* xr = (const float4*)(x + (size_t)n * D_DIM);
  float4* outr = (float4*)(out_q + (size_t)n * D_DIM);
  double s = 0.0;
#pragma unroll
  for (int i = 0; i < 2; ++i) {
    const int d4 = lane * 2 + i;
    float4 q = qr[d4];
    float4 xv = xr[d4];
    outr[d4] = q;
    double d0 = (double)xv.x - (double)q.x;
    double d1 = (double)xv.y - (double)q.y;
    double d2 = (double)xv.z - (double)q.z;
    double d3 = (double)xv.w - (double)q.w;
    s += d0 * d0 + d1 * d1 + d2 * d2 + d3 * d3;
  }
  for (int off = 32; off > 0; off >>= 1) s += __shfl_down(s, off, 64);
  if (lane == 0) {
    out_idx[n] = (float)idx;
    atomicAdd(&loss_part[(n * 37) & 255], s);
  }
}

__global__ void vq_loss(const double* __restrict__ loss_part,
                        float* __restrict__ out_s) {
  __shared__ double sm[256];
  const int t = threadIdx.x;
  sm[t] = loss_part[t];
  __syncthreads();
  for (int off = 128; off > 0; off >>= 1) {
    if (t < off) sm[t] += sm[t + off];
    __syncthreads();
  }
  if (t == 0) {
    double m = sm[0] / (double)(N_ROWS * D_DIM);
    out_s[0] = (float)(0.25 * m);
    out_s[1] = (float)m;
    out_s[2] = (float)(1.25 * m);
  }
}

extern "C" void kernel_launch(void* const* d_in, const int* in_sizes, int n_in,
                              void* d_out, int out_size, void* d_ws, size_t ws_size,
                              hipStream_t stream) {
  const float* x = (const float*)d_in[0];
  const float* emb = (const float*)d_in[1];
  float* out = (float*)d_out;

  // ws: [0,64K) u64 slots; [64K,96K) f32 x_sq; [96K,128K) f32 e_sq;
  //     [128K,130K) f64 loss_part[256]
  u64* slots = (u64*)d_ws;
  float* x_sq = (float*)((char*)d_ws + 65536);
  float* e_sq = (float*)((char*)d_ws + 98304);
  double* loss_part = (double*)((char*)d_ws + 131072);

  hipMemsetAsync(d_ws, 0xFF, 65536, stream);
  hipMemsetAsync(loss_part, 0, 256 * sizeof(double), stream);

  vq_sq<<<(2 * N_ROWS) / 256, 256, 0, stream>>>(x, emb, x_sq, e_sq);
  vq_dist<<<4096, 512, 0, stream>>>(x, emb, x_sq, e_sq, slots);
  vq_out<<<N_ROWS / 4, 256, 0, stream>>>(x, emb, slots, out,
                                         out + N_ROWS * D_DIM, loss_part);
  vq_loss<<<1, 256, 0, stream>>>(loss_part, out + N_ROWS * D_DIM + N_ROWS);
}

// Round 7
// 1026.174 us; speedup vs baseline: 1.1407x; 1.1407x over previous
//
#include <hip/hip_runtime.h>

#define N_ROWS 8192
#define K_CODES 8192
#define D_DIM 512

typedef unsigned long long u64;

// ---------------------------------------------------------------------------
// numpy pairwise summation of squares (bit-exact, unchanged from passing R3-R6).
// ---------------------------------------------------------------------------
__device__ __forceinline__ float pw_base128_sq(const float* __restrict__ p) {
  float r0 = __fmul_rn(p[0], p[0]);
  float r1 = __fmul_rn(p[1], p[1]);
  float r2 = __fmul_rn(p[2], p[2]);
  float r3 = __fmul_rn(p[3], p[3]);
  float r4 = __fmul_rn(p[4], p[4]);
  float r5 = __fmul_rn(p[5], p[5]);
  float r6 = __fmul_rn(p[6], p[6]);
  float r7 = __fmul_rn(p[7], p[7]);
  for (int i = 8; i < 128; i += 8) {
    r0 = __fadd_rn(r0, __fmul_rn(p[i + 0], p[i + 0]));
    r1 = __fadd_rn(r1, __fmul_rn(p[i + 1], p[i + 1]));
    r2 = __fadd_rn(r2, __fmul_rn(p[i + 2], p[i + 2]));
    r3 = __fadd_rn(r3, __fmul_rn(p[i + 3], p[i + 3]));
    r4 = __fadd_rn(r4, __fmul_rn(p[i + 4], p[i + 4]));
    r5 = __fadd_rn(r5, __fmul_rn(p[i + 5], p[i + 5]));
    r6 = __fadd_rn(r6, __fmul_rn(p[i + 6], p[i + 6]));
    r7 = __fadd_rn(r7, __fmul_rn(p[i + 7], p[i + 7]));
  }
  return __fadd_rn(__fadd_rn(__fadd_rn(r0, r1), __fadd_rn(r2, r3)),
                   __fadd_rn(__fadd_rn(r4, r5), __fadd_rn(r6, r7)));
}

__device__ __forceinline__ float pw_sq_512(const float* __restrict__ p) {
  float b0 = pw_base128_sq(p);
  float b1 = pw_base128_sq(p + 128);
  float b2 = pw_base128_sq(p + 256);
  float b3 = pw_base128_sq(p + 384);
  return __fadd_rn(__fadd_rn(b0, b1), __fadd_rn(b2, b3));
}

__global__ __launch_bounds__(256) void vq_sq(const float* __restrict__ x,
                                             const float* __restrict__ emb,
                                             float* __restrict__ x_sq,
                                             float* __restrict__ e_sq) {
  const int tid = blockIdx.x * 256 + threadIdx.x;
  if (tid < N_ROWS) {
    x_sq[tid] = pw_sq_512(x + tid * D_DIM);
  } else {
    const int k = tid - N_ROWS;
    e_sq[k] = pw_sq_512(emb + k * D_DIM);
  }
}

// ---------------------------------------------------------------------------
// Kernel 2: distance + argmin. Tile 64n x 256k per block (8 waves, 512 thr).
// Double-buffered LDS (2 x 32 KB), stage(next) issued before compute(cur),
// one vmcnt(0)+barrier per 32-dd chunk.
//
// launch_bounds(512,4): gfx950 occupancy counts VGPR+AGPR TOTAL (unified
// file). (512,2) let the allocator pick ~84V + ~64A = ~148 total -> 3
// waves/SIMD -> only ONE block resident -> barrier bubbles exposed (R6:
// occ 23%, VALUBusy 52%). (512,4) caps total at 128 -> 4 waves/SIMD ->
// 2 blocks/CU (R4: occ 45%, VALUBusy 83%). Macros (not arrays) for stage
// addressing keep scratch at zero (R6: WRITE_SIZE 147MB -> 8MB).
//
// FMA chain per output bit-identical to R3-R6 (ascending dd, split@384).
// ---------------------------------------------------------------------------
__device__ __forceinline__ void compute_chunk(const float* __restrict__ esb,
                                              const float* __restrict__ xw,
                                              int dd0, int lane,
                                              float (&acc)[8][4]) {
  const int ebase = lane * 128;
  const int lm = ((lane >> 1) & 7) ^ ((lane >> 4) & 3);  // f(4*lane+j), j<4
#pragma unroll
  for (int g = 0; g < 8; ++g) {
    const float* p = esb + ebase + 4 * (g ^ lm);
    const float4 ev0 = *reinterpret_cast<const float4*>(p);
    const float4 ev1 = *reinterpret_cast<const float4*>(p + 32);
    const float4 ev2 = *reinterpret_cast<const float4*>(p + 64);
    const float4 ev3 = *reinterpret_cast<const float4*>(p + 96);
#pragma unroll
    for (int r = 0; r < 8; ++r) {
      const float4 xv =
          *reinterpret_cast<const float4*>(xw + r * D_DIM + dd0 + 4 * g);
      float a0 = acc[r][0], a1 = acc[r][1], a2 = acc[r][2], a3 = acc[r][3];
      a0 = __fmaf_rn(xv.x, ev0.x, a0);
      a0 = __fmaf_rn(xv.y, ev0.y, a0);
      a0 = __fmaf_rn(xv.z, ev0.z, a0);
      a0 = __fmaf_rn(xv.w, ev0.w, a0);
      a1 = __fmaf_rn(xv.x, ev1.x, a1);
      a1 = __fmaf_rn(xv.y, ev1.y, a1);
      a1 = __fmaf_rn(xv.z, ev1.z, a1);
      a1 = __fmaf_rn(xv.w, ev1.w, a1);
      a2 = __fmaf_rn(xv.x, ev2.x, a2);
      a2 = __fmaf_rn(xv.y, ev2.y, a2);
      a2 = __fmaf_rn(xv.z, ev2.z, a2);
      a2 = __fmaf_rn(xv.w, ev2.w, a2);
      a3 = __fmaf_rn(xv.x, ev3.x, a3);
      a3 = __fmaf_rn(xv.y, ev3.y, a3);
      a3 = __fmaf_rn(xv.z, ev3.z, a3);
      a3 = __fmaf_rn(xv.w, ev3.w, a3);
      acc[r][0] = a0; acc[r][1] = a1; acc[r][2] = a2; acc[r][3] = a3;
    }
  }
}

// One global_load_lds: lane t stages 16 B to linear LDS (4t+2048I floats);
// global source dd-quad pre-swizzled by f(row) with row = (t>>3)+64I:
// f = ((t>>6)&7) ^ (I&3).
#define STAGE1(BUF, DD0, I)                                                    \
  __builtin_amdgcn_global_load_lds(                                            \
      (const __attribute__((address_space(1))) void*)(                         \
          e + (size_t)(k0 + (t >> 3) + 64 * (I)) * D_DIM + (DD0) +             \
          4 * ((t & 7) ^ ((t >> 6) & 7) ^ ((I) & 3))),                         \
      (__attribute__((address_space(3))) void*)(&es[BUF][4 * t + 2048 * (I)]), \
      16, 0, 0)
#define STAGE(BUF, DD0)                                                        \
  do {                                                                         \
    STAGE1(BUF, DD0, 0);                                                       \
    STAGE1(BUF, DD0, 1);                                                       \
    STAGE1(BUF, DD0, 2);                                                       \
    STAGE1(BUF, DD0, 3);                                                       \
  } while (0)

__global__ __launch_bounds__(512, 4) void vq_dist(
    const float* __restrict__ x, const float* __restrict__ e,
    const float* __restrict__ x_sq, const float* __restrict__ e_sq,
    u64* __restrict__ slots) {
  __shared__ float es[2][8192];  // 2 x 32 KB

  const int t = threadIdx.x;
  const int lane = t & 63;

  // XCD-aware bijective swizzle: 4096 blocks -> 512/XCD; one XCD works
  // through 128 consecutive n-blocks of the same k-panel (512 KB, L2-hot).
  const int bx = blockIdx.x;
  const int swz = (bx & 7) * 512 + (bx >> 3);
  const int kb = swz >> 7;    // 0..31
  const int nb = swz & 127;   // 0..127
  const int k0 = kb * 256;
  const int n0w = __builtin_amdgcn_readfirstlane(nb * 64 + (t >> 6) * 8);
  const float* xw = x + (size_t)n0w * D_DIM;

  float accA[8][4], accB[8][4];
#pragma unroll
  for (int r = 0; r < 8; ++r)
#pragma unroll
    for (int j = 0; j < 4; ++j) { accA[r][j] = 0.0f; accB[r][j] = 0.0f; }

  // Prologue: fill buffer 0 with chunk 0.
  STAGE(0, 0);
  asm volatile("s_waitcnt vmcnt(0)" ::: "memory");
  __syncthreads();

  // Phase A: chunks 0..11 (dd < 384).
#pragma unroll 1
  for (int c = 0; c < 12; ++c) {
    STAGE((c + 1) & 1, (c + 1) * 32);
    compute_chunk(&es[c & 1][0], xw, c * 32, lane, accA);
    asm volatile("s_waitcnt vmcnt(0)" ::: "memory");
    __syncthreads();
  }
  // Phase B: chunks 12..15 (dd >= 384).
#pragma unroll 1
  for (int c = 12; c < 16; ++c) {
    if (c < 15) STAGE((c + 1) & 1, (c + 1) * 32);
    compute_chunk(&es[c & 1][0], xw, c * 32, lane, accB);
    asm volatile("s_waitcnt vmcnt(0)" ::: "memory");
    __syncthreads();
  }

  // Epilogue: dist = fl(fl(x_sq - 2*dot) + e_sq); packed-key argmin.
  const float4 xsqa = *reinterpret_cast<const float4*>(x_sq + n0w);
  const float4 xsqb = *reinterpret_cast<const float4*>(x_sq + n0w + 4);
  const float xsq[8] = {xsqa.x, xsqa.y, xsqa.z, xsqa.w,
                        xsqb.x, xsqb.y, xsqb.z, xsqb.w};
  const int klane = k0 + lane * 4;
  const float4 esq = *reinterpret_cast<const float4*>(e_sq + klane);
  const float esqv[4] = {esq.x, esq.y, esq.z, esq.w};

#pragma unroll
  for (int r = 0; r < 8; ++r) {
    u64 best = ~0ULL;
#pragma unroll
    for (int j = 0; j < 4; ++j) {
      float dot = __fadd_rn(accA[r][j], accB[r][j]);
      float dist = __fadd_rn(__fsub_rn(xsq[r], __fmul_rn(2.0f, dot)), esqv[j]);
      unsigned int b = __float_as_uint(dist);
      unsigned int sb = (b & 0x80000000u) ? ~b : (b | 0x80000000u);
      u64 key = ((u64)sb << 32) | (unsigned)(klane + j);
      best = best < key ? best : key;
    }
#pragma unroll
    for (int off = 32; off > 0; off >>= 1) {
      u64 o = __shfl_xor((unsigned long long)best, off, 64);
      best = best < o ? best : o;
    }
    if (lane == 0) atomicMin(&slots[n0w + r], best);
  }
}

// ---------------------------------------------------------------------------
// Kernel 3: gather quantized rows (one wave per row), f32 outputs, loss
// partials into 256 hashed f64 buckets.
// ---------------------------------------------------------------------------
__global__ __launch_bounds__(256) void vq_out(
    const float* __restrict__ x, const float* __restrict__ e,
    const u64* __restrict__ slots, float* __restrict__ out_q,
    float* __restrict__ out_idx, double* __restrict__ loss_part) {
  const int t = threadIdx.x;
  const int w = t >> 6, lane = t & 63;
  const int n = blockIdx.x * 4 + w;
  const int idx = (int)(slots[n] & 0xFFFFFFFFULL);
  const float4* qr = (const float4*)(e + (size_t)idx * D_DIM);
  const float4* xr = (const float4*)(x + (size_t)n * D_DIM);
  float4* outr = (float4*)(out_q + (size_t)n * D_DIM);
  double s = 0.0;
#pragma unroll
  for (int i = 0; i < 2; ++i) {
    const int d4 = lane * 2 + i;
    float4 q = qr[d4];
    float4 xv = xr[d4];
    outr[d4] = q;
    double d0 = (double)xv.x - (double)q.x;
    double d1 = (double)xv.y - (double)q.y;
    double d2 = (double)xv.z - (double)q.z;
    double d3 = (double)xv.w - (double)q.w;
    s += d0 * d0 + d1 * d1 + d2 * d2 + d3 * d3;
  }
  for (int off = 32; off > 0; off >>= 1) s += __shfl_down(s, off, 64);
  if (lane == 0) {
    out_idx[n] = (float)idx;
    atomicAdd(&loss_part[(n * 37) & 255], s);
  }
}

__global__ void vq_loss(const double* __restrict__ loss_part,
                        float* __restrict__ out_s) {
  __shared__ double sm[256];
  const int t = threadIdx.x;
  sm[t] = loss_part[t];
  __syncthreads();
  for (int off = 128; off > 0; off >>= 1) {
    if (t < off) sm[t] += sm[t + off];
    __syncthreads();
  }
  if (t == 0) {
    double m = sm[0] / (double)(N_ROWS * D_DIM);
    out_s[0] = (float)(0.25 * m);
    out_s[1] = (float)m;
    out_s[2] = (float)(1.25 * m);
  }
}

extern "C" void kernel_launch(void* const* d_in, const int* in_sizes, int n_in,
                              void* d_out, int out_size, void* d_ws, size_t ws_size,
                              hipStream_t stream) {
  const float* x = (const float*)d_in[0];
  const float* emb = (const float*)d_in[1];
  float* out = (float*)d_out;

  // ws: [0,64K) u64 slots; [64K,96K) f32 x_sq; [96K,128K) f32 e_sq;
  //     [128K,130K) f64 loss_part[256]
  u64* slots = (u64*)d_ws;
  float* x_sq = (float*)((char*)d_ws + 65536);
  float* e_sq = (float*)((char*)d_ws + 98304);
  double* loss_part = (double*)((char*)d_ws + 131072);

  hipMemsetAsync(d_ws, 0xFF, 65536, stream);
  hipMemsetAsync(loss_part, 0, 256 * sizeof(double), stream);

  vq_sq<<<(2 * N_ROWS) / 256, 256, 0, stream>>>(x, emb, x_sq, e_sq);
  vq_dist<<<4096, 512, 0, stream>>>(x, emb, x_sq, e_sq, slots);
  vq_out<<<N_ROWS / 4, 256, 0, stream>>>(x, emb, slots, out,
                                         out + N_ROWS * D_DIM, loss_part);
  vq_loss<<<1, 256, 0, stream>>>(loss_part, out + N_ROWS * D_DIM + N_ROWS);
}

// Round 8
// 979.959 us; speedup vs baseline: 1.1945x; 1.0472x over previous
//
#include <hip/hip_runtime.h>

#define N_ROWS 8192
#define K_CODES 8192
#define D_DIM 512

typedef unsigned long long u64;

// ---------------------------------------------------------------------------
// numpy pairwise summation of squares (bit-exact, unchanged from passing R3-R7).
// ---------------------------------------------------------------------------
__device__ __forceinline__ float pw_base128_sq(const float* __restrict__ p) {
  float r0 = __fmul_rn(p[0], p[0]);
  float r1 = __fmul_rn(p[1], p[1]);
  float r2 = __fmul_rn(p[2], p[2]);
  float r3 = __fmul_rn(p[3], p[3]);
  float r4 = __fmul_rn(p[4], p[4]);
  float r5 = __fmul_rn(p[5], p[5]);
  float r6 = __fmul_rn(p[6], p[6]);
  float r7 = __fmul_rn(p[7], p[7]);
  for (int i = 8; i < 128; i += 8) {
    r0 = __fadd_rn(r0, __fmul_rn(p[i + 0], p[i + 0]));
    r1 = __fadd_rn(r1, __fmul_rn(p[i + 1], p[i + 1]));
    r2 = __fadd_rn(r2, __fmul_rn(p[i + 2], p[i + 2]));
    r3 = __fadd_rn(r3, __fmul_rn(p[i + 3], p[i + 3]));
    r4 = __fadd_rn(r4, __fmul_rn(p[i + 4], p[i + 4]));
    r5 = __fadd_rn(r5, __fmul_rn(p[i + 5], p[i + 5]));
    r6 = __fadd_rn(r6, __fmul_rn(p[i + 6], p[i + 6]));
    r7 = __fadd_rn(r7, __fmul_rn(p[i + 7], p[i + 7]));
  }
  return __fadd_rn(__fadd_rn(__fadd_rn(r0, r1), __fadd_rn(r2, r3)),
                   __fadd_rn(__fadd_rn(r4, r5), __fadd_rn(r6, r7)));
}

__device__ __forceinline__ float pw_sq_512(const float* __restrict__ p) {
  float b0 = pw_base128_sq(p);
  float b1 = pw_base128_sq(p + 128);
  float b2 = pw_base128_sq(p + 256);
  float b3 = pw_base128_sq(p + 384);
  return __fadd_rn(__fadd_rn(b0, b1), __fadd_rn(b2, b3));
}

__global__ __launch_bounds__(256) void vq_sq(const float* __restrict__ x,
                                             const float* __restrict__ emb,
                                             float* __restrict__ x_sq,
                                             float* __restrict__ e_sq) {
  const int tid = blockIdx.x * 256 + threadIdx.x;
  if (tid < N_ROWS) {
    x_sq[tid] = pw_sq_512(x + tid * D_DIM);
  } else {
    const int k = tid - N_ROWS;
    e_sq[k] = pw_sq_512(emb + k * D_DIM);
  }
}

// ---------------------------------------------------------------------------
// Kernel 2: distance + argmin. Tile 64n x 128k per block (8 waves, 512 thr),
// per-thread micro-tile 8n x 2k  =>  live acc = 32 floats (not 64).
//
// R5-R7 lesson: accA[8][4]+accB[8][4] = 64 floats cannot coexist with a
// 64-reg cap (spills: 147 MB scratch, R5/R7) and without the cap the
// allocator picks ~148 total regs -> 1 block/CU (R6). Halving j to 2 puts
// the whole working set (~55-70 regs) under the no-spill threshold while
// LDS drops to 2x16 KB/block -> >=3 blocks/CU, bubbles cross-covered.
// launch_bounds(512,6): VGPR cap ~85 = no-spill guarantee; occupancy
// floats to 6-8 waves/SIMD per actual allocation.
//
// LDS: 128 k-rows x 32 dd, quad-swizzle f(row) = (row>>1)&7 (lanes read
// rows 2*lane+j -> 8-lane groups cover all 8 quad-columns, conflict-free).
// Staging: linear LDS dest (global_load_lds), source dd-quad pre-swizzled:
// (t&7) ^ ((t>>4)&7)  (I-independent).
//
// FMA chain per output bit-identical to R3-R7 (ascending dd, split@384).
// ---------------------------------------------------------------------------
__device__ __forceinline__ void compute_chunk(const float* __restrict__ esb,
                                              const float* __restrict__ xw,
                                              int dd0, int lane,
                                              float (&acc)[8][2]) {
  const int rbase = lane * 64;  // (2*lane) * 32 floats/row
  const int lm = lane & 7;      // f(2*lane+j) for j in {0,1}
#pragma unroll
  for (int g = 0; g < 8; ++g) {
    const float* p = esb + rbase + 4 * (g ^ lm);
    const float4 ev0 = *reinterpret_cast<const float4*>(p);        // row 2*lane
    const float4 ev1 = *reinterpret_cast<const float4*>(p + 32);   // row 2*lane+1
#pragma unroll
    for (int r = 0; r < 8; ++r) {
      const float4 xv =
          *reinterpret_cast<const float4*>(xw + r * D_DIM + dd0 + 4 * g);
      float a0 = acc[r][0], a1 = acc[r][1];
      a0 = __fmaf_rn(xv.x, ev0.x, a0);
      a0 = __fmaf_rn(xv.y, ev0.y, a0);
      a0 = __fmaf_rn(xv.z, ev0.z, a0);
      a0 = __fmaf_rn(xv.w, ev0.w, a0);
      a1 = __fmaf_rn(xv.x, ev1.x, a1);
      a1 = __fmaf_rn(xv.y, ev1.y, a1);
      a1 = __fmaf_rn(xv.z, ev1.z, a1);
      a1 = __fmaf_rn(xv.w, ev1.w, a1);
      acc[r][0] = a0;
      acc[r][1] = a1;
    }
  }
}

// Lane t stages 16 B to linear LDS (float idx 4t + 2048I, I=0..1);
// global source row (t>>3)+64I, dd-quad (t&7)^((t>>4)&7).
#define STAGE1(BUF, DD0, I)                                                    \
  __builtin_amdgcn_global_load_lds(                                            \
      (const __attribute__((address_space(1))) void*)(                         \
          e + (size_t)(k0 + (t >> 3) + 64 * (I)) * D_DIM + (DD0) +             \
          4 * ((t & 7) ^ ((t >> 4) & 7))),                                     \
      (__attribute__((address_space(3))) void*)(&es[BUF][4 * t + 2048 * (I)]), \
      16, 0, 0)
#define STAGE(BUF, DD0)                                                        \
  do {                                                                         \
    STAGE1(BUF, DD0, 0);                                                       \
    STAGE1(BUF, DD0, 1);                                                       \
  } while (0)

__global__ __launch_bounds__(512, 6) void vq_dist(
    const float* __restrict__ x, const float* __restrict__ e,
    const float* __restrict__ x_sq, const float* __restrict__ e_sq,
    u64* __restrict__ slots) {
  __shared__ float es[2][4096];  // 2 x 16 KB

  const int t = threadIdx.x;
  const int lane = t & 63;

  // XCD-aware bijective swizzle: 8192 blocks -> 1024/XCD; consecutive swz
  // on one XCD share a k-panel (128k x 512d = 256 KB, L2-hot).
  const int bx = blockIdx.x;
  const int swz = (bx & 7) * 1024 + (bx >> 3);
  const int kb = swz >> 7;    // 0..63
  const int nb = swz & 127;   // 0..127
  const int k0 = kb * 128;
  const int n0w = __builtin_amdgcn_readfirstlane(nb * 64 + (t >> 6) * 8);
  const float* xw = x + (size_t)n0w * D_DIM;

  float accA[8][2], accB[8][2];
#pragma unroll
  for (int r = 0; r < 8; ++r) {
    accA[r][0] = 0.0f; accA[r][1] = 0.0f;
    accB[r][0] = 0.0f; accB[r][1] = 0.0f;
  }

  // Prologue: fill buffer 0 with chunk 0.
  STAGE(0, 0);
  asm volatile("s_waitcnt vmcnt(0)" ::: "memory");
  __syncthreads();

  // Phase A: chunks 0..11 (dd < 384).
#pragma unroll 1
  for (int c = 0; c < 12; ++c) {
    STAGE((c + 1) & 1, (c + 1) * 32);
    compute_chunk(&es[c & 1][0], xw, c * 32, lane, accA);
    asm volatile("s_waitcnt vmcnt(0)" ::: "memory");
    __syncthreads();
  }
  // Phase B: chunks 12..15 (dd >= 384).
#pragma unroll 1
  for (int c = 12; c < 16; ++c) {
    if (c < 15) STAGE((c + 1) & 1, (c + 1) * 32);
    compute_chunk(&es[c & 1][0], xw, c * 32, lane, accB);
    asm volatile("s_waitcnt vmcnt(0)" ::: "memory");
    __syncthreads();
  }

  // Epilogue: dist = fl(fl(x_sq - 2*dot) + e_sq); packed-key argmin.
  const float4 xsqa = *reinterpret_cast<const float4*>(x_sq + n0w);
  const float4 xsqb = *reinterpret_cast<const float4*>(x_sq + n0w + 4);
  const float xsq[8] = {xsqa.x, xsqa.y, xsqa.z, xsqa.w,
                        xsqb.x, xsqb.y, xsqb.z, xsqb.w};
  const int klane = k0 + 2 * lane;
  const float2 esq = *reinterpret_cast<const float2*>(e_sq + klane);
  const float esqv[2] = {esq.x, esq.y};

#pragma unroll
  for (int r = 0; r < 8; ++r) {
    u64 best = ~0ULL;
#pragma unroll
    for (int j = 0; j < 2; ++j) {
      float dot = __fadd_rn(accA[r][j], accB[r][j]);
      float dist = __fadd_rn(__fsub_rn(xsq[r], __fmul_rn(2.0f, dot)), esqv[j]);
      unsigned int b = __float_as_uint(dist);
      unsigned int sb = (b & 0x80000000u) ? ~b : (b | 0x80000000u);
      u64 key = ((u64)sb << 32) | (unsigned)(klane + j);
      best = best < key ? best : key;
    }
#pragma unroll
    for (int off = 32; off > 0; off >>= 1) {
      u64 o = __shfl_xor((unsigned long long)best, off, 64);
      best = best < o ? best : o;
    }
    if (lane == 0) atomicMin(&slots[n0w + r], best);
  }
}

// ---------------------------------------------------------------------------
// Kernel 3: gather quantized rows (one wave per row), f32 outputs, loss
// partials into 256 hashed f64 buckets.
// ---------------------------------------------------------------------------
__global__ __launch_bounds__(256) void vq_out(
    const float* __restrict__ x, const float* __restrict__ e,
    const u64* __restrict__ slots, float* __restrict__ out_q,
    float* __restrict__ out_idx, double* __restrict__ loss_part) {
  const int t = threadIdx.x;
  const int w = t >> 6, lane = t & 63;
  const int n = blockIdx.x * 4 + w;
  const int idx = (int)(slots[n] & 0xFFFFFFFFULL);
  const float4* qr = (const float4*)(e + (size_t)idx * D_DIM);
  const float4* xr = (const float4*)(x + (size_t)n * D_DIM);
  float4* outr = (float4*)(out_q + (size_t)n * D_DIM);
  double s = 0.0;
#pragma unroll
  for (int i = 0; i < 2; ++i) {
    const int d4 = lane * 2 + i;
    float4 q = qr[d4];
    float4 xv = xr[d4];
    outr[d4] = q;
    double d0 = (double)xv.x - (double)q.x;
    double d1 = (double)xv.y - (double)q.y;
    double d2 = (double)xv.z - (double)q.z;
    double d3 = (double)xv.w - (double)q.w;
    s += d0 * d0 + d1 * d1 + d2 * d2 + d3 * d3;
  }
  for (int off = 32; off > 0; off >>= 1) s += __shfl_down(s, off, 64);
  if (lane == 0) {
    out_idx[n] = (float)idx;
    atomicAdd(&loss_part[(n * 37) & 255], s);
  }
}

__global__ void vq_loss(const double* __restrict__ loss_part,
                        float* __restrict__ out_s) {
  __shared__ double sm[256];
  const int t = threadIdx.x;
  sm[t] = loss_part[t];
  __syncthreads();
  for (int off = 128; off > 0; off >>= 1) {
    if (t < off) sm[t] += sm[t + off];
    __syncthreads();
  }
  if (t == 0) {
    double m = sm[0] / (double)(N_ROWS * D_DIM);
    out_s[0] = (float)(0.25 * m);
    out_s[1] = (float)m;
    out_s[2] = (float)(1.25 * m);
  }
}

extern "C" void kernel_launch(void* const* d_in, const int* in_sizes, int n_in,
                              void* d_out, int out_size, void* d_ws, size_t ws_size,
                              hipStream_t stream) {
  const float* x = (const float*)d_in[0];
  const float* emb = (const float*)d_in[1];
  float* out = (float*)d_out;

  // ws: [0,64K) u64 slots; [64K,96K) f32 x_sq; [96K,128K) f32 e_sq;
  //     [128K,130K) f64 loss_part[256]
  u64* slots = (u64*)d_ws;
  float* x_sq = (float*)((char*)d_ws + 65536);
  float* e_sq = (float*)((char*)d_ws + 98304);
  double* loss_part = (double*)((char*)d_ws + 131072);

  hipMemsetAsync(d_ws, 0xFF, 65536, stream);
  hipMemsetAsync(loss_part, 0, 256 * sizeof(double), stream);

  vq_sq<<<(2 * N_ROWS) / 256, 256, 0, stream>>>(x, emb, x_sq, e_sq);
  vq_dist<<<8192, 512, 0, stream>>>(x, emb, x_sq, e_sq, slots);
  vq_out<<<N_ROWS / 4, 256, 0, stream>>>(x, emb, slots, out,
                                         out + N_ROWS * D_DIM, loss_part);
  vq_loss<<<1, 256, 0, stream>>>(loss_part, out + N_ROWS * D_DIM + N_ROWS);
}